// Round 1
// baseline (417.569 us; speedup 1.0000x reference)
//
#include <hip/hip_runtime.h>
#include <hip/hip_bf16.h>

#define NN 100000
#define NE 1600000
#define BK 98               // row buckets: row >> 10, rows 0..99999 -> 0..97
#define CAP 18432           // slots per bucket region (mean 16384, sigma ~127)
#define CHUNK 8192          // edges per phase-A workgroup

typedef _Float16 f16;
typedef f16 f16x8 __attribute__((ext_vector_type(8)));
typedef float f32x4 __attribute__((ext_vector_type(4)));

// ---------------- adjacency build: two-phase binned CSR ----------------

__global__ void zero_i32(int* __restrict__ p, int n) {
    int i = blockIdx.x * blockDim.x + threadIdx.x;
    if (i < n) p[i] = 0;
}

// Phase A: counting-sort each 8192-edge chunk by bucket in LDS, stream grouped
// runs contiguously into per-bucket regions.
__global__ __launch_bounds__(256) void bin_edges(const int* __restrict__ row,
                                                 const int* __restrict__ col,
                                                 int* __restrict__ bcursor,
                                                 int2* __restrict__ binned) {
    __shared__ int  bcnt[BK];
    __shared__ int  bbase[BK];
    __shared__ int  lstart[BK + 1];
    __shared__ int  bcur[BK];
    __shared__ int2 stage[CHUNK];
    int tid = threadIdx.x;
    int e0 = blockIdx.x * CHUNK;
    int emax = min(CHUNK, NE - e0);

    if (tid < BK) bcnt[tid] = 0;
    __syncthreads();
    for (int i = tid; i < emax; i += 256)
        atomicAdd(&bcnt[row[e0 + i] >> 10], 1);
    __syncthreads();
    if (tid == 0) {
        int s = 0;
        for (int b = 0; b < BK; ++b) { lstart[b] = s; s += bcnt[b]; }
        lstart[BK] = s;
    }
    __syncthreads();
    if (tid < BK) {
        bcur[tid]  = lstart[tid];
        bbase[tid] = atomicAdd(&bcursor[tid], bcnt[tid]);  // run start within bucket
    }
    __syncthreads();
    for (int i = tid; i < emax; i += 256) {
        int r = row[e0 + i], c = col[e0 + i];
        int pos = atomicAdd(&bcur[r >> 10], 1);
        stage[pos] = make_int2(r, c);
    }
    __syncthreads();
    for (int i = tid; i < emax; i += 256) {
        int2 rc = stage[i];
        int b = rc.x >> 10;
        binned[(size_t)b * CAP + bbase[b] + (i - lstart[b])] = rc;
    }
}

// Phase B: one WG per bucket. Build local CSR in LDS, stream out contiguously.
__global__ __launch_bounds__(1024) void build_csr(const int* __restrict__ bcount,
                                                  const int2* __restrict__ binned,
                                                  int* __restrict__ offsets,
                                                  float* __restrict__ dinv,
                                                  int* __restrict__ csr_col) {
    __shared__ int cnt[1024];
    __shared__ int sc[1024];
    __shared__ int colbuf[CAP];
    __shared__ int mybase_s;
    int tid = threadIdx.x;
    int b = blockIdx.x;
    int r0 = b << 10;
    int nrows = min(1024, NN - r0);

    if (tid < BK) sc[tid] = bcount[tid];
    cnt[tid] = 0;
    __syncthreads();
    if (tid == 0) {
        int s = 0;
        for (int i = 0; i < b; ++i) s += sc[i];
        mybase_s = s;
    }
    int n = sc[b];
    __syncthreads();
    int mybase = mybase_s;
    const int2* src = binned + (size_t)b * CAP;

    for (int i = tid; i < n; i += 1024)
        atomicAdd(&cnt[src[i].x - r0], 1);
    __syncthreads();

    // inclusive scan of cnt -> sc
    int v = cnt[tid];
    sc[tid] = v;
    __syncthreads();
    #pragma unroll
    for (int s = 1; s < 1024; s <<= 1) {
        int t = (tid >= s) ? sc[tid - s] : 0;
        __syncthreads();
        sc[tid] += t;
        __syncthreads();
    }
    int incl = sc[tid];
    if (tid < nrows) {
        offsets[r0 + tid + 1] = mybase + incl;
        dinv[r0 + tid] = rsqrtf((float)(v + 1));   // +1 self loop
    }
    if (b == 0 && tid == 0) offsets[0] = 0;

    cnt[tid] = incl - v;   // exclusive -> local cursor
    __syncthreads();
    for (int i = tid; i < n; i += 1024) {
        int2 rc = src[i];
        int pos = atomicAdd(&cnt[rc.x - r0], 1);
        colbuf[pos] = rc.y;
    }
    __syncthreads();
    for (int i = tid; i < n; i += 1024)
        csr_col[mybase + i] = colbuf[i];
}

// ---------------- MFMA f16 GEMM ----------------
// Output T is CHUNK-MAJOR: Tc[F/16][NN][16] f16, chunk slice = 3.2 MB (< 4 MiB
// per-XCD L2) so the downstream gather can be made L2-resident per XCD.
// f16 input A (Hbuf) is also chunk-major [128/16][NN][16]; fp32 input (x) is
// row-major [NN][128].
template<int F, bool AFP32>
__global__ __launch_bounds__(256) void gemm_mfma(const void* __restrict__ Ain,
                                                 const float* __restrict__ W,
                                                 const float* __restrict__ dinv,
                                                 f16* __restrict__ T) {
    constexpr int PITCH = 136;
    __shared__ f16 Wt[F * PITCH];
    int tid = threadIdx.x;
    for (int e = tid; e < 128 * F; e += 256) {
        int k = e / F, n = e - k * F;
        Wt[n * PITCH + k] = (f16)W[e];
    }
    __syncthreads();

    int wave = tid >> 6;
    int lane = tid & 63;
    int m = lane & 15, q = lane >> 4;
    int r0 = blockIdx.x * 64 + wave * 16;
    int ra = min(r0 + m, NN - 1);

    constexpr int NT = F / 16;
    f32x4 acc[NT];
    #pragma unroll
    for (int t = 0; t < NT; ++t) acc[t] = (f32x4){0.f, 0.f, 0.f, 0.f};

    #pragma unroll
    for (int c = 0; c < 4; ++c) {            // K = 128 = 4 x 32
        f16x8 a;
        if constexpr (AFP32) {
            const float* Af = (const float*)Ain;
            const float4* p = (const float4*)&Af[(size_t)ra * 128 + c * 32 + q * 8];
            float4 lo = p[0], hi = p[1];
            a[0] = (f16)lo.x; a[1] = (f16)lo.y; a[2] = (f16)lo.z; a[3] = (f16)lo.w;
            a[4] = (f16)hi.x; a[5] = (f16)hi.y; a[6] = (f16)hi.z; a[7] = (f16)hi.w;
        } else {
            // chunk-major H: features c*32+q*8 .. +7 live in chunk kc at offset (q&1)*8
            const f16* Ah = (const f16*)Ain;
            int kc = 2 * c + (q >> 1);
            a = *(const f16x8*)&Ah[((size_t)kc * NN + ra) * 16 + (q & 1) * 8];
        }
        #pragma unroll
        for (int t = 0; t < NT; ++t) {
            f16x8 b = *(const f16x8*)&Wt[(t * 16 + m) * PITCH + c * 32 + q * 8];
            acc[t] = __builtin_amdgcn_mfma_f32_16x16x32_f16(a, b, acc[t], 0, 0, 0);
        }
    }

    int rows[4];
    float dv[4];
    #pragma unroll
    for (int i = 0; i < 4; ++i) {
        rows[i] = r0 + q * 4 + i;
        dv[i] = dinv[min(rows[i], NN - 1)];
    }
    // chunk index == t (m < 16), within-chunk feature == m
    #pragma unroll
    for (int t = 0; t < NT; ++t) {
        #pragma unroll
        for (int i = 0; i < 4; ++i) {
            if (rows[i] < NN) {
                T[((size_t)t * NN + rows[i]) * 16 + m] = (f16)(acc[t][i] * dv[i]);
            }
        }
    }
}

// ---------------- SpMM gather on chunk-major f16 T ----------------
// One block = ONE 16-feature chunk x 128 rows. chunk = blockIdx % NCH so that
// under round-robin blockIdx->XCD mapping, each XCD gathers only from its own
// 3.2 MB chunk slice -> L2-resident working set (vs 25.6 MB before).
// 2 lanes per row, each lane owns 8 features (16 B gather per lane).
template<int F, bool RELU, bool OUTF16>
__global__ __launch_bounds__(256) void spmm_h(const f16* __restrict__ T,
                                              const int* __restrict__ offsets,
                                              const int* __restrict__ csr_col,
                                              const float* __restrict__ dinv,
                                              const float* __restrict__ bias,
                                              void* __restrict__ outv) {
    constexpr int NCH = F / 16;
    int c  = blockIdx.x % NCH;          // chunk -> fixed XCD (blockIdx % 8 affinity)
    int rb = blockIdx.x / NCH;
    int lane = threadIdx.x & 1;         // which f16x8 half of the chunk
    int rs   = threadIdx.x >> 1;        // 0..127
    int r    = rb * 128 + rs;
    if (r >= NN) return;

    const f16x8* Tv = (const f16x8*)(T + (size_t)c * NN * 16);
    int o0 = offsets[r], o1 = offsets[r + 1];

    float s0[8], s1[8], s2[8], s3[8];
    f16x8 self = Tv[(size_t)r * 2 + lane];
    #pragma unroll
    for (int u = 0; u < 8; ++u) { s0[u] = (float)self[u]; s1[u] = 0.f; s2[u] = 0.f; s3[u] = 0.f; }

    int j = o0;
    for (; j + 4 <= o1; j += 4) {
        int c0 = csr_col[j], c1 = csr_col[j + 1], c2 = csr_col[j + 2], c3 = csr_col[j + 3];
        f16x8 v0 = Tv[(size_t)c0 * 2 + lane];
        f16x8 v1 = Tv[(size_t)c1 * 2 + lane];
        f16x8 v2 = Tv[(size_t)c2 * 2 + lane];
        f16x8 v3 = Tv[(size_t)c3 * 2 + lane];
        #pragma unroll
        for (int u = 0; u < 8; ++u) {
            s0[u] += (float)v0[u]; s1[u] += (float)v1[u];
            s2[u] += (float)v2[u]; s3[u] += (float)v3[u];
        }
    }
    for (; j < o1; ++j) {
        int cc = csr_col[j];
        f16x8 v = Tv[(size_t)cc * 2 + lane];
        #pragma unroll
        for (int u = 0; u < 8; ++u) s0[u] += (float)v[u];
    }

    float dr = dinv[r];
    float o[8];
    #pragma unroll
    for (int u = 0; u < 8; ++u) {
        float s = (s0[u] + s1[u]) + (s2[u] + s3[u]);
        o[u] = fmaf(dr, s, bias[c * 16 + lane * 8 + u]);
        if (RELU) o[u] = fmaxf(o[u], 0.f);
    }

    if (OUTF16) {
        // chunk-major H out: contiguous 16 B per lane, fully coalesced per block
        f16x8 h;
        #pragma unroll
        for (int u = 0; u < 8; ++u) h[u] = (f16)o[u];
        ((f16x8*)outv)[((size_t)c * NN + r) * 2 + lane] = h;
    } else {
        // final fp32 output stays row-major [NN][F]
        float* outF = (float*)outv;
        float4 lo = make_float4(o[0], o[1], o[2], o[3]);
        float4 hi = make_float4(o[4], o[5], o[6], o[7]);
        *(float4*)&outF[(size_t)r * F + c * 16 + lane * 8]     = lo;
        *(float4*)&outF[(size_t)r * F + c * 16 + lane * 8 + 4] = hi;
    }
}

// ---------------- launch ----------------

extern "C" void kernel_launch(void* const* d_in, const int* in_sizes, int n_in,
                              void* d_out, int out_size, void* d_ws, size_t ws_size,
                              hipStream_t stream) {
    const float* x  = (const float*)d_in[0];
    const int*   ei = (const int*)d_in[1];
    const float* W0 = (const float*)d_in[2];
    const float* b0 = (const float*)d_in[3];
    const float* W1 = (const float*)d_in[4];
    const float* b1 = (const float*)d_in[5];
    const float* W2 = (const float*)d_in[6];
    const float* b2 = (const float*)d_in[7];
    float* out = (float*)d_out;

    const int* row = ei;
    const int* col = ei + NE;

    char* wsp = (char*)d_ws;
    auto alloc = [&](size_t bytes) {
        char* p = wsp;
        wsp += (bytes + 255) & ~(size_t)255;
        return p;
    };
    int*   bcursor = (int*)alloc((size_t)BK * 4);          // run cursor, ends as bucket count
    int2*  binned  = (int2*)alloc((size_t)BK * CAP * 8);   // 14.5 MB
    int*   offsets = (int*)alloc((size_t)(NN + 1) * 4);
    float* dinv    = (float*)alloc((size_t)NN * 4);
    int*   csr_col = (int*)alloc((size_t)NE * 4);
    f16*   Tbuf    = (f16*)alloc((size_t)NN * 128 * 2);    // chunk-major [F/16][NN][16]
    f16*   Hbuf    = (f16*)alloc((size_t)NN * 128 * 2);    // chunk-major [8][NN][16]

    // adjacency build: bin -> per-bucket LDS CSR
    zero_i32<<<1, 256, 0, stream>>>(bcursor, BK);
    bin_edges<<<(NE + CHUNK - 1) / CHUNK, 256, 0, stream>>>(row, col, bcursor, binned);
    build_csr<<<BK, 1024, 0, stream>>>(bcursor, binned, offsets, dinv, csr_col);

    const int GB = (NN + 63) / 64;
    const int RB = (NN + 127) / 128;   // rowblocks per spmm chunk

    // layer 1
    gemm_mfma<128, true><<<GB, 256, 0, stream>>>(x, W0, dinv, Tbuf);
    spmm_h<128, true, true><<<8 * RB, 256, 0, stream>>>(Tbuf, offsets, csr_col, dinv, b0, Hbuf);
    // layer 2
    gemm_mfma<128, false><<<GB, 256, 0, stream>>>(Hbuf, W1, dinv, Tbuf);
    spmm_h<128, true, true><<<8 * RB, 256, 0, stream>>>(Tbuf, offsets, csr_col, dinv, b1, Hbuf);
    // layer 3 (no relu) -> fp32 d_out
    gemm_mfma<64, false><<<GB, 256, 0, stream>>>(Hbuf, W2, dinv, Tbuf);
    spmm_h<64, false, false><<<4 * RB, 256, 0, stream>>>(Tbuf, offsets, csr_col, dinv, b2, out);
}

// Round 2
// 346.371 us; speedup vs baseline: 1.2056x; 1.2056x over previous
//
#include <hip/hip_runtime.h>
#include <hip/hip_bf16.h>

#define NN 100000
#define NE 1600000
#define BK 98               // row buckets: row >> 10, rows 0..99999 -> 0..97
#define CAP 18432           // slots per bucket region (mean 16384, sigma ~127)
#define CHUNK 8192          // edges per phase-A workgroup

typedef _Float16 f16;
typedef f16 f16x8 __attribute__((ext_vector_type(8)));
typedef float f32x4 __attribute__((ext_vector_type(4)));

// ---------------- adjacency build: two-phase binned CSR ----------------

// Phase A: counting-sort each 8192-edge chunk by bucket in LDS, stream grouped
// runs contiguously into per-bucket regions.
__global__ __launch_bounds__(256) void bin_edges(const int* __restrict__ row,
                                                 const int* __restrict__ col,
                                                 int* __restrict__ bcursor,
                                                 int2* __restrict__ binned) {
    __shared__ int  bcnt[BK];
    __shared__ int  bbase[BK];
    __shared__ int  lstart[BK + 1];
    __shared__ int  bcur[BK];
    __shared__ int2 stage[CHUNK];
    int tid = threadIdx.x;
    int e0 = blockIdx.x * CHUNK;
    int emax = min(CHUNK, NE - e0);

    if (tid < BK) bcnt[tid] = 0;
    __syncthreads();
    for (int i = tid; i < emax; i += 256)
        atomicAdd(&bcnt[row[e0 + i] >> 10], 1);
    __syncthreads();
    if (tid == 0) {
        int s = 0;
        for (int b = 0; b < BK; ++b) { lstart[b] = s; s += bcnt[b]; }
        lstart[BK] = s;
    }
    __syncthreads();
    if (tid < BK) {
        bcur[tid]  = lstart[tid];
        bbase[tid] = atomicAdd(&bcursor[tid], bcnt[tid]);  // run start within bucket
    }
    __syncthreads();
    for (int i = tid; i < emax; i += 256) {
        int r = row[e0 + i], c = col[e0 + i];
        int pos = atomicAdd(&bcur[r >> 10], 1);
        stage[pos] = make_int2(r, c);
    }
    __syncthreads();
    for (int i = tid; i < emax; i += 256) {
        int2 rc = stage[i];
        int b = rc.x >> 10;
        binned[(size_t)b * CAP + bbase[b] + (i - lstart[b])] = rc;
    }
}

// Phase B: one WG per bucket. Build local CSR in LDS, stream out contiguously.
__global__ __launch_bounds__(1024) void build_csr(const int* __restrict__ bcount,
                                                  const int2* __restrict__ binned,
                                                  int* __restrict__ offsets,
                                                  float* __restrict__ dinv,
                                                  int* __restrict__ csr_col) {
    __shared__ int cnt[1024];
    __shared__ int sc[1024];
    __shared__ int colbuf[CAP];
    __shared__ int mybase_s;
    int tid = threadIdx.x;
    int b = blockIdx.x;
    int r0 = b << 10;
    int nrows = min(1024, NN - r0);

    if (tid < BK) sc[tid] = bcount[tid];
    cnt[tid] = 0;
    __syncthreads();
    if (tid == 0) {
        int s = 0;
        for (int i = 0; i < b; ++i) s += sc[i];
        mybase_s = s;
    }
    int n = sc[b];
    __syncthreads();
    int mybase = mybase_s;
    const int2* src = binned + (size_t)b * CAP;

    for (int i = tid; i < n; i += 1024)
        atomicAdd(&cnt[src[i].x - r0], 1);
    __syncthreads();

    // inclusive scan of cnt -> sc
    int v = cnt[tid];
    sc[tid] = v;
    __syncthreads();
    #pragma unroll
    for (int s = 1; s < 1024; s <<= 1) {
        int t = (tid >= s) ? sc[tid - s] : 0;
        __syncthreads();
        sc[tid] += t;
        __syncthreads();
    }
    int incl = sc[tid];
    if (tid < nrows) {
        offsets[r0 + tid + 1] = mybase + incl;
        dinv[r0 + tid] = rsqrtf((float)(v + 1));   // +1 self loop
    }
    if (b == 0 && tid == 0) offsets[0] = 0;

    cnt[tid] = incl - v;   // exclusive -> local cursor
    __syncthreads();
    for (int i = tid; i < n; i += 1024) {
        int2 rc = src[i];
        int pos = atomicAdd(&cnt[rc.x - r0], 1);
        colbuf[pos] = rc.y;
    }
    __syncthreads();
    for (int i = tid; i < n; i += 1024)
        csr_col[mybase + i] = colbuf[i];
}

// ---------------- MFMA f16 GEMM: T[N,F] = f16( dinv[r] * (A[N,128] @ W[128,F]) ) ----------------
// (round-0 layout: T row-major; used only for layer 1, fp32 input x)
template<int F, bool AFP32>
__global__ __launch_bounds__(256) void gemm_mfma(const void* __restrict__ Ain,
                                                 const float* __restrict__ W,
                                                 const float* __restrict__ dinv,
                                                 f16* __restrict__ T) {
    constexpr int PITCH = 136;
    __shared__ f16 Wt[F * PITCH];
    int tid = threadIdx.x;
    for (int e = tid; e < 128 * F; e += 256) {
        int k = e / F, n = e - k * F;
        Wt[n * PITCH + k] = (f16)W[e];
    }
    __syncthreads();

    int wave = tid >> 6;
    int lane = tid & 63;
    int m = lane & 15, q = lane >> 4;
    int r0 = blockIdx.x * 64 + wave * 16;
    int ra = min(r0 + m, NN - 1);

    constexpr int NT = F / 16;
    f32x4 acc[NT];
    #pragma unroll
    for (int t = 0; t < NT; ++t) acc[t] = (f32x4){0.f, 0.f, 0.f, 0.f};

    #pragma unroll
    for (int c = 0; c < 4; ++c) {            // K = 128 = 4 x 32
        f16x8 a;
        if constexpr (AFP32) {
            const float* Af = (const float*)Ain;
            const float4* p = (const float4*)&Af[(size_t)ra * 128 + c * 32 + q * 8];
            float4 lo = p[0], hi = p[1];
            a[0] = (f16)lo.x; a[1] = (f16)lo.y; a[2] = (f16)lo.z; a[3] = (f16)lo.w;
            a[4] = (f16)hi.x; a[5] = (f16)hi.y; a[6] = (f16)hi.z; a[7] = (f16)hi.w;
        } else {
            const f16* Ah = (const f16*)Ain;
            a = *(const f16x8*)&Ah[(size_t)ra * 128 + c * 32 + q * 8];
        }
        #pragma unroll
        for (int t = 0; t < NT; ++t) {
            f16x8 b = *(const f16x8*)&Wt[(t * 16 + m) * PITCH + c * 32 + q * 8];
            acc[t] = __builtin_amdgcn_mfma_f32_16x16x32_f16(a, b, acc[t], 0, 0, 0);
        }
    }

    int rows[4];
    float dv[4];
    #pragma unroll
    for (int i = 0; i < 4; ++i) {
        rows[i] = r0 + q * 4 + i;
        dv[i] = dinv[min(rows[i], NN - 1)];
    }
    #pragma unroll
    for (int t = 0; t < NT; ++t) {
        #pragma unroll
        for (int i = 0; i < 4; ++i) {
            if (rows[i] < NN) {
                T[(size_t)rows[i] * F + t * 16 + m] = (f16)(acc[t][i] * dv[i]);
            }
        }
    }
}

// ---------------- FUSED: SpMM gather (round-0 pattern) + next-layer GEMM ----------------
// 512 threads = 32 rows x 16 lanes. Gather phase identical in structure to the
// verified 62us spmm_h<128> (16 lanes/row, 256 B contiguous per edge = full-line
// payloads -> best transaction efficiency). Then h (post bias+relu) goes to LDS
// and 8 waves compute Tout[32, F2] = f16(dinv * (h[32,128] @ W[128,F2])) via MFMA,
// eliminating the Hbuf round-trip (51 MB/layer) and one dispatch.
// Grid MUST be exactly NN/32 blocks (NN % 32 == 0): no early-return allowed
// (barriers), and no row guard needed.
template<int F2>
__global__ __launch_bounds__(512, 6) void spmm_gemm(const f16* __restrict__ T,
                                                    const int* __restrict__ offsets,
                                                    const int* __restrict__ csr_col,
                                                    const float* __restrict__ dinv,
                                                    const float* __restrict__ bias,
                                                    const float* __restrict__ W,
                                                    f16* __restrict__ Tout) {
    constexpr int PITCH = 136;                 // f16 units; 272 B rows, 16B-aligned
    __shared__ f16 Wt[F2 * PITCH];             // W transposed [n][k]
    __shared__ f16 hbuf[32 * PITCH];           // 32 rows of h (and out-bounce)
    int tid = threadIdx.x;

    // stage W (fp32 -> f16, n-major); completion guaranteed by the barrier below
    for (int e = tid; e < 128 * F2; e += 512) {
        int k = e / F2, n = e - k * F2;
        Wt[n * PITCH + k] = (f16)W[e];
    }

    // ---- gather phase (identical access pattern to round-0 spmm_h<128>) ----
    int lane = tid & 15;                       // 16 lanes per row, 16 B each
    int rs   = tid >> 4;                       // 0..31
    int r    = blockIdx.x * 32 + rs;

    const f16x8* Tv = (const f16x8*)T;
    int o0 = offsets[r], o1 = offsets[r + 1];

    float s0[8], s1[8], s2[8], s3[8];
    f16x8 self = Tv[(size_t)r * 16 + lane];
    #pragma unroll
    for (int u = 0; u < 8; ++u) { s0[u] = (float)self[u]; s1[u] = 0.f; s2[u] = 0.f; s3[u] = 0.f; }

    int j = o0;
    for (; j + 4 <= o1; j += 4) {
        int c0 = csr_col[j], c1 = csr_col[j + 1], c2 = csr_col[j + 2], c3 = csr_col[j + 3];
        f16x8 v0 = Tv[(size_t)c0 * 16 + lane];
        f16x8 v1 = Tv[(size_t)c1 * 16 + lane];
        f16x8 v2 = Tv[(size_t)c2 * 16 + lane];
        f16x8 v3 = Tv[(size_t)c3 * 16 + lane];
        #pragma unroll
        for (int u = 0; u < 8; ++u) {
            s0[u] += (float)v0[u]; s1[u] += (float)v1[u];
            s2[u] += (float)v2[u]; s3[u] += (float)v3[u];
        }
    }
    for (; j < o1; ++j) {
        int c = csr_col[j];
        f16x8 v = Tv[(size_t)c * 16 + lane];
        #pragma unroll
        for (int u = 0; u < 8; ++u) s0[u] += (float)v[u];
    }

    float dr = dinv[r];
    f16x8 h;
    #pragma unroll
    for (int u = 0; u < 8; ++u) {
        float s = (s0[u] + s1[u]) + (s2[u] + s3[u]);
        float o = fmaf(dr, s, bias[lane * 8 + u]);
        h[u] = (f16)fmaxf(o, 0.f);             // both fused layers have relu
    }
    *(f16x8*)&hbuf[rs * PITCH + lane * 8] = h;
    __syncthreads();                            // h + Wt complete

    // ---- MFMA phase: 8 waves; wave = (row half rg) x (feature group fg) ----
    int wv = tid >> 6, wl = tid & 63;
    int m = wl & 15, q = wl >> 4;
    constexpr int FW  = F2 / 4;                 // feats per wave: 32 (F2=128) or 16
    constexpr int NTW = FW / 16;                // tiles per wave: 2 or 1
    int rg = wv >> 2;                           // 0..1
    int fg = wv & 3;                            // 0..3

    f32x4 acc[NTW];
    #pragma unroll
    for (int t = 0; t < NTW; ++t) acc[t] = (f32x4){0.f, 0.f, 0.f, 0.f};

    #pragma unroll
    for (int c = 0; c < 4; ++c) {
        f16x8 a = *(const f16x8*)&hbuf[(rg * 16 + m) * PITCH + c * 32 + q * 8];
        #pragma unroll
        for (int t = 0; t < NTW; ++t) {
            f16x8 b = *(const f16x8*)&Wt[(fg * FW + t * 16 + m) * PITCH + c * 32 + q * 8];
            acc[t] = __builtin_amdgcn_mfma_f32_16x16x32_f16(a, b, acc[t], 0, 0, 0);
        }
    }
    __syncthreads();                            // all A-reads done before hbuf reuse

    // ---- dinv scale + LDS bounce for coalesced f16 writeout ----
    #pragma unroll
    for (int i = 0; i < 4; ++i) {
        int rloc = rg * 16 + q * 4 + i;
        float dv = dinv[blockIdx.x * 32 + rloc];
        #pragma unroll
        for (int t = 0; t < NTW; ++t)
            hbuf[rloc * PITCH + fg * FW + t * 16 + m] = (f16)(acc[t][i] * dv);
    }
    __syncthreads();

    constexpr int LPO = F2 / 8;                 // f16x8 per row
    for (int e = tid; e < 32 * LPO; e += 512) {
        int rr = e / LPO, ff = e - rr * LPO;
        ((f16x8*)Tout)[(size_t)(blockIdx.x * 32 + rr) * LPO + ff] =
            *(f16x8*)&hbuf[rr * PITCH + ff * 8];
    }
}

// ---------------- SpMM gather on f16 T (round-0 layout; final layer) ----------------
template<int F, bool RELU, bool OUTF16>
__global__ __launch_bounds__(256) void spmm_h(const f16* __restrict__ T,
                                              const int* __restrict__ offsets,
                                              const int* __restrict__ csr_col,
                                              const float* __restrict__ dinv,
                                              const float* __restrict__ bias,
                                              void* __restrict__ outv) {
    constexpr int LPR = F / 8;
    constexpr int RPB = 256 / LPR;
    int lane = threadIdx.x % LPR;
    int rs   = threadIdx.x / LPR;
    int r    = blockIdx.x * RPB + rs;
    if (r >= NN) return;

    const f16x8* Tv = (const f16x8*)T;
    int o0 = offsets[r], o1 = offsets[r + 1];

    float s0[8], s1[8], s2[8], s3[8];
    f16x8 self = Tv[(size_t)r * LPR + lane];
    #pragma unroll
    for (int u = 0; u < 8; ++u) { s0[u] = (float)self[u]; s1[u] = 0.f; s2[u] = 0.f; s3[u] = 0.f; }

    int j = o0;
    for (; j + 4 <= o1; j += 4) {
        int c0 = csr_col[j], c1 = csr_col[j + 1], c2 = csr_col[j + 2], c3 = csr_col[j + 3];
        f16x8 v0 = Tv[(size_t)c0 * LPR + lane];
        f16x8 v1 = Tv[(size_t)c1 * LPR + lane];
        f16x8 v2 = Tv[(size_t)c2 * LPR + lane];
        f16x8 v3 = Tv[(size_t)c3 * LPR + lane];
        #pragma unroll
        for (int u = 0; u < 8; ++u) {
            s0[u] += (float)v0[u]; s1[u] += (float)v1[u];
            s2[u] += (float)v2[u]; s3[u] += (float)v3[u];
        }
    }
    for (; j < o1; ++j) {
        int c = csr_col[j];
        f16x8 v = Tv[(size_t)c * LPR + lane];
        #pragma unroll
        for (int u = 0; u < 8; ++u) s0[u] += (float)v[u];
    }

    float dr = dinv[r];
    float o[8];
    #pragma unroll
    for (int u = 0; u < 8; ++u) {
        float s = (s0[u] + s1[u]) + (s2[u] + s3[u]);
        o[u] = fmaf(dr, s, bias[lane * 8 + u]);
        if (RELU) o[u] = fmaxf(o[u], 0.f);
    }

    if (OUTF16) {
        f16x8 h;
        #pragma unroll
        for (int u = 0; u < 8; ++u) h[u] = (f16)o[u];
        ((f16x8*)outv)[(size_t)r * LPR + lane] = h;
    } else {
        float* outF = (float*)outv;
        float4 lo = make_float4(o[0], o[1], o[2], o[3]);
        float4 hi = make_float4(o[4], o[5], o[6], o[7]);
        *(float4*)&outF[(size_t)r * F + lane * 8]     = lo;
        *(float4*)&outF[(size_t)r * F + lane * 8 + 4] = hi;
    }
}

// ---------------- launch ----------------

extern "C" void kernel_launch(void* const* d_in, const int* in_sizes, int n_in,
                              void* d_out, int out_size, void* d_ws, size_t ws_size,
                              hipStream_t stream) {
    const float* x  = (const float*)d_in[0];
    const int*   ei = (const int*)d_in[1];
    const float* W0 = (const float*)d_in[2];
    const float* b0 = (const float*)d_in[3];
    const float* W1 = (const float*)d_in[4];
    const float* b1 = (const float*)d_in[5];
    const float* W2 = (const float*)d_in[6];
    const float* b2 = (const float*)d_in[7];
    float* out = (float*)d_out;

    const int* row = ei;
    const int* col = ei + NE;

    char* wsp = (char*)d_ws;
    auto alloc = [&](size_t bytes) {
        char* p = wsp;
        wsp += (bytes + 255) & ~(size_t)255;
        return p;
    };
    int*   bcursor = (int*)alloc((size_t)BK * 4);          // run cursor, ends as bucket count
    int2*  binned  = (int2*)alloc((size_t)BK * CAP * 8);   // 14.5 MB
    int*   offsets = (int*)alloc((size_t)(NN + 1) * 4);
    float* dinv    = (float*)alloc((size_t)NN * 4);
    int*   csr_col = (int*)alloc((size_t)NE * 4);
    f16*   Tbuf    = (f16*)alloc((size_t)NN * 128 * 2);
    f16*   Hbuf    = (f16*)alloc((size_t)NN * 128 * 2);

    // adjacency build
    hipMemsetAsync(bcursor, 0, (size_t)BK * 4, stream);
    bin_edges<<<(NE + CHUNK - 1) / CHUNK, 256, 0, stream>>>(row, col, bcursor, binned);
    build_csr<<<BK, 1024, 0, stream>>>(bcursor, binned, offsets, dinv, csr_col);

    const int GB = (NN + 63) / 64;
    const int FB = NN / 32;            // 3125, exact (NN % 32 == 0)

    // layer 1 GEMM (fp32 x): T1 = f16(dinv * (x @ W0))
    gemm_mfma<128, true><<<GB, 256, 0, stream>>>(x, W0, dinv, Tbuf);
    // fused: H1 = relu(spmm(T1) + b0);  T2 = f16(dinv * (H1 @ W1))
    spmm_gemm<128><<<FB, 512, 0, stream>>>(Tbuf, offsets, csr_col, dinv, b0, W1, Hbuf);
    // fused: H2 = relu(spmm(T2) + b1);  T3 = f16(dinv * (H2 @ W2))
    spmm_gemm<64><<<FB, 512, 0, stream>>>(Hbuf, offsets, csr_col, dinv, b1, W2, Tbuf);
    // final: out = spmm(T3) + b2   (fp32, no relu)
    spmm_h<64, false, false><<<(NN + 31) / 32, 256, 0, stream>>>(Tbuf, offsets, csr_col, dinv, b2, out);
}

// Round 3
// 335.126 us; speedup vs baseline: 1.2460x; 1.0336x over previous
//
#include <hip/hip_runtime.h>
#include <hip/hip_bf16.h>

#define NN 100000
#define NE 1600000
#define BK2 391             // row buckets: row >> 8, rows 0..99999 -> 0..390
#define CAP2 4864           // slots per bucket (mean 4096, sigma ~64, +12 sigma)
#define CHUNK2 4096         // edges per phase-A workgroup (391 blocks)

typedef _Float16 f16;
typedef f16 f16x8 __attribute__((ext_vector_type(8)));
typedef float f32x4 __attribute__((ext_vector_type(4)));

// ---------------- adjacency build: two-phase binned CSR (391-way) ----------------

// Phase A: counting-sort each 4096-edge chunk by 256-row bucket in LDS, stream
// grouped runs contiguously into per-bucket regions. Parallel ping-pong scan
// replaces the old serial thread-0 prefix; 391 buckets cut LDS-atomic
// contention ~8x vs the 98-bucket version.
__global__ __launch_bounds__(256) void bin_edges(const int* __restrict__ row,
                                                 const int* __restrict__ col,
                                                 int* __restrict__ bcursor,
                                                 int2* __restrict__ binned) {
    __shared__ int  bcnt[BK2];
    __shared__ int  bbase[BK2];
    __shared__ int  lstart[BK2];
    __shared__ int  bcur[BK2];
    __shared__ int  sca[BK2];
    __shared__ int  scb[BK2];
    __shared__ int2 stage[CHUNK2];
    int tid = threadIdx.x;
    int e0 = blockIdx.x * CHUNK2;
    int emax = min(CHUNK2, NE - e0);

    for (int i = tid; i < BK2; i += 256) bcnt[i] = 0;
    __syncthreads();
    for (int i = tid; i < emax; i += 256)
        atomicAdd(&bcnt[row[e0 + i] >> 8], 1);
    __syncthreads();

    // parallel inclusive scan of bcnt (ping-pong, 9 rounds)
    for (int i = tid; i < BK2; i += 256) sca[i] = bcnt[i];
    __syncthreads();
    int* pa = sca; int* pb = scb;
    for (int s = 1; s < BK2; s <<= 1) {
        for (int i = tid; i < BK2; i += 256)
            pb[i] = pa[i] + ((i >= s) ? pa[i - s] : 0);
        __syncthreads();
        int* t = pa; pa = pb; pb = t;
    }
    for (int i = tid; i < BK2; i += 256) {
        int ex = pa[i] - bcnt[i];              // exclusive
        lstart[i] = ex;
        bcur[i]   = ex;
        bbase[i]  = atomicAdd(&bcursor[i], bcnt[i]);   // run start within bucket
    }
    __syncthreads();

    for (int i = tid; i < emax; i += 256) {
        int r = row[e0 + i], c = col[e0 + i];
        int pos = atomicAdd(&bcur[r >> 8], 1);
        stage[pos] = make_int2(r, c);
    }
    __syncthreads();
    for (int i = tid; i < emax; i += 256) {
        int2 rc = stage[i];
        int b = rc.x >> 8;
        binned[(size_t)b * CAP2 + bbase[b] + (i - lstart[b])] = rc;
    }
}

// Phase B: one 256-thread WG per 256-row bucket (391 blocks). Build local CSR
// in LDS, stream csr_col/offsets/dinv out contiguously.
__global__ __launch_bounds__(256) void build_csr(const int* __restrict__ bcount,
                                                 const int2* __restrict__ binned,
                                                 int* __restrict__ offsets,
                                                 float* __restrict__ dinv,
                                                 int* __restrict__ csr_col) {
    __shared__ int cnt[256];
    __shared__ int sc[256];
    __shared__ int red[256];
    __shared__ int colbuf[CAP2];
    int tid = threadIdx.x;
    int b = blockIdx.x;
    int r0 = b << 8;
    int nrows = min(256, NN - r0);

    // global base = sum bcount[0..b-1], parallel reduce
    int part = 0;
    for (int i = tid; i < b; i += 256) part += bcount[i];
    red[tid] = part;
    cnt[tid] = 0;
    __syncthreads();
    #pragma unroll
    for (int s = 128; s > 0; s >>= 1) {
        if (tid < s) red[tid] += red[tid + s];
        __syncthreads();
    }
    int mybase = red[0];
    int n = bcount[b];
    const int2* src = binned + (size_t)b * CAP2;

    for (int i = tid; i < n; i += 256)
        atomicAdd(&cnt[src[i].x - r0], 1);
    __syncthreads();

    // inclusive scan of cnt -> sc (8 rounds)
    int v = cnt[tid];
    sc[tid] = v;
    __syncthreads();
    #pragma unroll
    for (int s = 1; s < 256; s <<= 1) {
        int t = (tid >= s) ? sc[tid - s] : 0;
        __syncthreads();
        sc[tid] += t;
        __syncthreads();
    }
    int incl = sc[tid];
    if (tid < nrows) {
        offsets[r0 + tid + 1] = mybase + incl;
        dinv[r0 + tid] = rsqrtf((float)(v + 1));   // +1 self loop
    }
    if (b == 0 && tid == 0) offsets[0] = 0;

    cnt[tid] = incl - v;   // exclusive -> local cursor
    __syncthreads();
    for (int i = tid; i < n; i += 256) {
        int2 rc = src[i];
        int pos = atomicAdd(&cnt[rc.x - r0], 1);
        colbuf[pos] = rc.y;
    }
    __syncthreads();
    for (int i = tid; i < n; i += 256)
        csr_col[mybase + i] = colbuf[i];
}

// ---------------- MFMA f16 GEMM: T[N,F] = f16( dinv[r] * (A[N,128] @ W[128,F]) ) ----------------
template<int F, bool AFP32>
__global__ __launch_bounds__(256) void gemm_mfma(const void* __restrict__ Ain,
                                                 const float* __restrict__ W,
                                                 const float* __restrict__ dinv,
                                                 f16* __restrict__ T) {
    constexpr int PITCH = 136;
    __shared__ f16 Wt[F * PITCH];
    int tid = threadIdx.x;
    for (int e = tid; e < 128 * F; e += 256) {
        int k = e / F, n = e - k * F;
        Wt[n * PITCH + k] = (f16)W[e];
    }
    __syncthreads();

    int wave = tid >> 6;
    int lane = tid & 63;
    int m = lane & 15, q = lane >> 4;
    int r0 = blockIdx.x * 64 + wave * 16;
    int ra = min(r0 + m, NN - 1);

    constexpr int NT = F / 16;
    f32x4 acc[NT];
    #pragma unroll
    for (int t = 0; t < NT; ++t) acc[t] = (f32x4){0.f, 0.f, 0.f, 0.f};

    #pragma unroll
    for (int c = 0; c < 4; ++c) {            // K = 128 = 4 x 32
        f16x8 a;
        if constexpr (AFP32) {
            const float* Af = (const float*)Ain;
            const float4* p = (const float4*)&Af[(size_t)ra * 128 + c * 32 + q * 8];
            float4 lo = p[0], hi = p[1];
            a[0] = (f16)lo.x; a[1] = (f16)lo.y; a[2] = (f16)lo.z; a[3] = (f16)lo.w;
            a[4] = (f16)hi.x; a[5] = (f16)hi.y; a[6] = (f16)hi.z; a[7] = (f16)hi.w;
        } else {
            const f16* Ah = (const f16*)Ain;
            a = *(const f16x8*)&Ah[(size_t)ra * 128 + c * 32 + q * 8];
        }
        #pragma unroll
        for (int t = 0; t < NT; ++t) {
            f16x8 b = *(const f16x8*)&Wt[(t * 16 + m) * PITCH + c * 32 + q * 8];
            acc[t] = __builtin_amdgcn_mfma_f32_16x16x32_f16(a, b, acc[t], 0, 0, 0);
        }
    }

    int rows[4];
    float dv[4];
    #pragma unroll
    for (int i = 0; i < 4; ++i) {
        rows[i] = r0 + q * 4 + i;
        dv[i] = dinv[min(rows[i], NN - 1)];
    }
    #pragma unroll
    for (int t = 0; t < NT; ++t) {
        #pragma unroll
        for (int i = 0; i < 4; ++i) {
            if (rows[i] < NN) {
                T[(size_t)rows[i] * F + t * 16 + m] = (f16)(acc[t][i] * dv[i]);
            }
        }
    }
}

// ---------------- FUSED: SpMM gather + next-layer GEMM ----------------
// 512 threads = 32 rows x 16 lanes. Gather unrolled 8-wide (8 outstanding 16 B
// loads per lane) with 2 accumulator sets to stay inside the VGPR-85 budget
// of __launch_bounds__(512,6). Grid must be exactly NN/32 blocks.
template<int F2>
__global__ __launch_bounds__(512, 6) void spmm_gemm(const f16* __restrict__ T,
                                                    const int* __restrict__ offsets,
                                                    const int* __restrict__ csr_col,
                                                    const float* __restrict__ dinv,
                                                    const float* __restrict__ bias,
                                                    const float* __restrict__ W,
                                                    f16* __restrict__ Tout) {
    constexpr int PITCH = 136;                 // f16 units; 272 B rows, 16B-aligned
    __shared__ f16 Wt[F2 * PITCH];             // W transposed [n][k]
    __shared__ f16 hbuf[32 * PITCH];           // 32 rows of h (and out-bounce)
    int tid = threadIdx.x;

    // stage W (fp32 -> f16, n-major); completion guaranteed by the barrier below
    for (int e = tid; e < 128 * F2; e += 512) {
        int k = e / F2, n = e - k * F2;
        Wt[n * PITCH + k] = (f16)W[e];
    }

    // ---- gather phase ----
    int lane = tid & 15;                       // 16 lanes per row, 16 B each
    int rs   = tid >> 4;                       // 0..31
    int r    = blockIdx.x * 32 + rs;

    const f16x8* Tv = (const f16x8*)T;
    int o0 = offsets[r], o1 = offsets[r + 1];

    float s0[8], s1[8];
    f16x8 self = Tv[(size_t)r * 16 + lane];
    #pragma unroll
    for (int u = 0; u < 8; ++u) { s0[u] = (float)self[u]; s1[u] = 0.f; }

    int j = o0;
    for (; j + 8 <= o1; j += 8) {
        int c0 = csr_col[j],     c1 = csr_col[j + 1], c2 = csr_col[j + 2], c3 = csr_col[j + 3];
        int c4 = csr_col[j + 4], c5 = csr_col[j + 5], c6 = csr_col[j + 6], c7 = csr_col[j + 7];
        f16x8 v0 = Tv[(size_t)c0 * 16 + lane];
        f16x8 v1 = Tv[(size_t)c1 * 16 + lane];
        f16x8 v2 = Tv[(size_t)c2 * 16 + lane];
        f16x8 v3 = Tv[(size_t)c3 * 16 + lane];
        f16x8 v4 = Tv[(size_t)c4 * 16 + lane];
        f16x8 v5 = Tv[(size_t)c5 * 16 + lane];
        f16x8 v6 = Tv[(size_t)c6 * 16 + lane];
        f16x8 v7 = Tv[(size_t)c7 * 16 + lane];
        #pragma unroll
        for (int u = 0; u < 8; ++u) {
            s0[u] += (float)v0[u] + (float)v2[u];
            s1[u] += (float)v1[u] + (float)v3[u];
            s0[u] += (float)v4[u] + (float)v6[u];
            s1[u] += (float)v5[u] + (float)v7[u];
        }
    }
    for (; j + 4 <= o1; j += 4) {
        int c0 = csr_col[j], c1 = csr_col[j + 1], c2 = csr_col[j + 2], c3 = csr_col[j + 3];
        f16x8 v0 = Tv[(size_t)c0 * 16 + lane];
        f16x8 v1 = Tv[(size_t)c1 * 16 + lane];
        f16x8 v2 = Tv[(size_t)c2 * 16 + lane];
        f16x8 v3 = Tv[(size_t)c3 * 16 + lane];
        #pragma unroll
        for (int u = 0; u < 8; ++u) {
            s0[u] += (float)v0[u] + (float)v2[u];
            s1[u] += (float)v1[u] + (float)v3[u];
        }
    }
    for (; j < o1; ++j) {
        int c = csr_col[j];
        f16x8 v = Tv[(size_t)c * 16 + lane];
        #pragma unroll
        for (int u = 0; u < 8; ++u) s0[u] += (float)v[u];
    }

    float dr = dinv[r];
    f16x8 h;
    #pragma unroll
    for (int u = 0; u < 8; ++u) {
        float s = s0[u] + s1[u];
        float o = fmaf(dr, s, bias[lane * 8 + u]);
        h[u] = (f16)fmaxf(o, 0.f);             // both fused layers have relu
    }
    *(f16x8*)&hbuf[rs * PITCH + lane * 8] = h;
    __syncthreads();                            // h + Wt complete

    // ---- MFMA phase: 8 waves; wave = (row half rg) x (feature group fg) ----
    int wv = tid >> 6, wl = tid & 63;
    int m = wl & 15, q = wl >> 4;
    constexpr int FW  = F2 / 4;                 // feats per wave: 32 (F2=128) or 16
    constexpr int NTW = FW / 16;                // tiles per wave: 2 or 1
    int rg = wv >> 2;                           // 0..1
    int fg = wv & 3;                            // 0..3

    f32x4 acc[NTW];
    #pragma unroll
    for (int t = 0; t < NTW; ++t) acc[t] = (f32x4){0.f, 0.f, 0.f, 0.f};

    #pragma unroll
    for (int c = 0; c < 4; ++c) {
        f16x8 a = *(const f16x8*)&hbuf[(rg * 16 + m) * PITCH + c * 32 + q * 8];
        #pragma unroll
        for (int t = 0; t < NTW; ++t) {
            f16x8 b = *(const f16x8*)&Wt[(fg * FW + t * 16 + m) * PITCH + c * 32 + q * 8];
            acc[t] = __builtin_amdgcn_mfma_f32_16x16x32_f16(a, b, acc[t], 0, 0, 0);
        }
    }
    __syncthreads();                            // all A-reads done before hbuf reuse

    // ---- dinv scale + LDS bounce for coalesced f16 writeout ----
    #pragma unroll
    for (int i = 0; i < 4; ++i) {
        int rloc = rg * 16 + q * 4 + i;
        float dv = dinv[blockIdx.x * 32 + rloc];
        #pragma unroll
        for (int t = 0; t < NTW; ++t)
            hbuf[rloc * PITCH + fg * FW + t * 16 + m] = (f16)(acc[t][i] * dv);
    }
    __syncthreads();

    constexpr int LPO = F2 / 8;                 // f16x8 per row
    for (int e = tid; e < 32 * LPO; e += 512) {
        int rr = e / LPO, ff = e - rr * LPO;
        ((f16x8*)Tout)[(size_t)(blockIdx.x * 32 + rr) * LPO + ff] =
            *(f16x8*)&hbuf[rr * PITCH + ff * 8];
    }
}

// ---------------- SpMM gather on f16 T (final layer) ----------------
template<int F, bool RELU, bool OUTF16>
__global__ __launch_bounds__(256) void spmm_h(const f16* __restrict__ T,
                                              const int* __restrict__ offsets,
                                              const int* __restrict__ csr_col,
                                              const float* __restrict__ dinv,
                                              const float* __restrict__ bias,
                                              void* __restrict__ outv) {
    constexpr int LPR = F / 8;
    constexpr int RPB = 256 / LPR;
    int lane = threadIdx.x % LPR;
    int rs   = threadIdx.x / LPR;
    int r    = blockIdx.x * RPB + rs;
    if (r >= NN) return;

    const f16x8* Tv = (const f16x8*)T;
    int o0 = offsets[r], o1 = offsets[r + 1];

    float s0[8], s1[8];
    f16x8 self = Tv[(size_t)r * LPR + lane];
    #pragma unroll
    for (int u = 0; u < 8; ++u) { s0[u] = (float)self[u]; s1[u] = 0.f; }

    int j = o0;
    for (; j + 8 <= o1; j += 8) {
        int c0 = csr_col[j],     c1 = csr_col[j + 1], c2 = csr_col[j + 2], c3 = csr_col[j + 3];
        int c4 = csr_col[j + 4], c5 = csr_col[j + 5], c6 = csr_col[j + 6], c7 = csr_col[j + 7];
        f16x8 v0 = Tv[(size_t)c0 * LPR + lane];
        f16x8 v1 = Tv[(size_t)c1 * LPR + lane];
        f16x8 v2 = Tv[(size_t)c2 * LPR + lane];
        f16x8 v3 = Tv[(size_t)c3 * LPR + lane];
        f16x8 v4 = Tv[(size_t)c4 * LPR + lane];
        f16x8 v5 = Tv[(size_t)c5 * LPR + lane];
        f16x8 v6 = Tv[(size_t)c6 * LPR + lane];
        f16x8 v7 = Tv[(size_t)c7 * LPR + lane];
        #pragma unroll
        for (int u = 0; u < 8; ++u) {
            s0[u] += (float)v0[u] + (float)v2[u];
            s1[u] += (float)v1[u] + (float)v3[u];
            s0[u] += (float)v4[u] + (float)v6[u];
            s1[u] += (float)v5[u] + (float)v7[u];
        }
    }
    for (; j + 4 <= o1; j += 4) {
        int c0 = csr_col[j], c1 = csr_col[j + 1], c2 = csr_col[j + 2], c3 = csr_col[j + 3];
        f16x8 v0 = Tv[(size_t)c0 * LPR + lane];
        f16x8 v1 = Tv[(size_t)c1 * LPR + lane];
        f16x8 v2 = Tv[(size_t)c2 * LPR + lane];
        f16x8 v3 = Tv[(size_t)c3 * LPR + lane];
        #pragma unroll
        for (int u = 0; u < 8; ++u) {
            s0[u] += (float)v0[u] + (float)v2[u];
            s1[u] += (float)v1[u] + (float)v3[u];
        }
    }
    for (; j < o1; ++j) {
        int c = csr_col[j];
        f16x8 v = Tv[(size_t)c * LPR + lane];
        #pragma unroll
        for (int u = 0; u < 8; ++u) s0[u] += (float)v[u];
    }

    float dr = dinv[r];
    float o[8];
    #pragma unroll
    for (int u = 0; u < 8; ++u) {
        float s = s0[u] + s1[u];
        o[u] = fmaf(dr, s, bias[lane * 8 + u]);
        if (RELU) o[u] = fmaxf(o[u], 0.f);
    }

    if (OUTF16) {
        f16x8 h;
        #pragma unroll
        for (int u = 0; u < 8; ++u) h[u] = (f16)o[u];
        ((f16x8*)outv)[(size_t)r * LPR + lane] = h;
    } else {
        float* outF = (float*)outv;
        float4 lo = make_float4(o[0], o[1], o[2], o[3]);
        float4 hi = make_float4(o[4], o[5], o[6], o[7]);
        *(float4*)&outF[(size_t)r * F + lane * 8]     = lo;
        *(float4*)&outF[(size_t)r * F + lane * 8 + 4] = hi;
    }
}

// ---------------- launch ----------------

extern "C" void kernel_launch(void* const* d_in, const int* in_sizes, int n_in,
                              void* d_out, int out_size, void* d_ws, size_t ws_size,
                              hipStream_t stream) {
    const float* x  = (const float*)d_in[0];
    const int*   ei = (const int*)d_in[1];
    const float* W0 = (const float*)d_in[2];
    const float* b0 = (const float*)d_in[3];
    const float* W1 = (const float*)d_in[4];
    const float* b1 = (const float*)d_in[5];
    const float* W2 = (const float*)d_in[6];
    const float* b2 = (const float*)d_in[7];
    float* out = (float*)d_out;

    const int* row = ei;
    const int* col = ei + NE;

    char* wsp = (char*)d_ws;
    auto alloc = [&](size_t bytes) {
        char* p = wsp;
        wsp += (bytes + 255) & ~(size_t)255;
        return p;
    };
    int*   bcursor = (int*)alloc((size_t)BK2 * 4);          // run cursor, ends as bucket count
    int2*  binned  = (int2*)alloc((size_t)BK2 * CAP2 * 8);  // 15.2 MB
    int*   offsets = (int*)alloc((size_t)(NN + 1) * 4);
    float* dinv    = (float*)alloc((size_t)NN * 4);
    int*   csr_col = (int*)alloc((size_t)NE * 4);
    f16*   Tbuf    = (f16*)alloc((size_t)NN * 128 * 2);
    f16*   Hbuf    = (f16*)alloc((size_t)NN * 128 * 2);

    // adjacency build
    hipMemsetAsync(bcursor, 0, (size_t)BK2 * 4, stream);
    bin_edges<<<(NE + CHUNK2 - 1) / CHUNK2, 256, 0, stream>>>(row, col, bcursor, binned);
    build_csr<<<BK2, 256, 0, stream>>>(bcursor, binned, offsets, dinv, csr_col);

    const int GB = (NN + 63) / 64;
    const int FB = NN / 32;            // 3125, exact (NN % 32 == 0)

    // layer 1 GEMM (fp32 x): T1 = f16(dinv * (x @ W0))
    gemm_mfma<128, true><<<GB, 256, 0, stream>>>(x, W0, dinv, Tbuf);
    // fused: H1 = relu(spmm(T1) + b0);  T2 = f16(dinv * (H1 @ W1))
    spmm_gemm<128><<<FB, 512, 0, stream>>>(Tbuf, offsets, csr_col, dinv, b0, W1, Hbuf);
    // fused: H2 = relu(spmm(T2) + b1);  T3 = f16(dinv * (H2 @ W2))
    spmm_gemm<64><<<FB, 512, 0, stream>>>(Hbuf, offsets, csr_col, dinv, b1, W2, Tbuf);
    // final: out = spmm(T3) + b2   (fp32, no relu)
    spmm_h<64, false, false><<<(NN + 31) / 32, 256, 0, stream>>>(Tbuf, offsets, csr_col, dinv, b2, out);
}